// Round 6
// baseline (235.298 us; speedup 1.0000x reference)
//
#include <hip/hip_runtime.h>
#include <hip/hip_bf16.h>
#include <math.h>

// Problem constants (fixed by the reference)
#define BB 32
#define LL 768
#define DD 256
#define FF 256
#define TT 3072
#define MT 32              // output rows (l positions) per conv block
#define OS 257             // output-tile row stride (floats): odd -> column access conflict-free

typedef __attribute__((ext_vector_type(8))) short bf16x8;
typedef __attribute__((ext_vector_type(4))) float f32x4;

__device__ inline unsigned short f2b(float f) {
    union { float f; unsigned u; } v; v.f = f;
    unsigned r = (v.u + 0x7FFF + ((v.u >> 16) & 1)) >> 16;  // RNE
    return (unsigned short)r;
}

// ---------------------------------------------------------------------------
// Weight prep into FRAGMENT-MAJOR layout:
//   wQ[s*8192 + n*32 + q*8 + j] = bf16(w[kc][cin][n])
//   s = kc*8 + c8 (K-step), cin = c8*32 + q*8 + j
// so a B-fragment load (step s, wave, nt) is one contiguous 1 KB wave-burst.
// ---------------------------------------------------------------------------
__global__ __launch_bounds__(256) void prep_w_kernel(
    const float* __restrict__ w1, const float* __restrict__ w2,
    unsigned short* __restrict__ wQ1, unsigned short* __restrict__ wQ2)
{
    const int layer = blockIdx.x / 24;
    const int s  = blockIdx.x % 24;
    const int kc = s >> 3, c8 = s & 7;
    const float* __restrict__ w = layer ? w2 : w1;
    unsigned short* __restrict__ o = (layer ? wQ2 : wQ1) + s * 8192 + threadIdx.x * 32;
    const int n = threadIdx.x;

    alignas(16) unsigned short tmp[32];
#pragma unroll
    for (int q = 0; q < 4; ++q)
#pragma unroll
        for (int j = 0; j < 8; ++j) {
            const int cin = c8 * 32 + q * 8 + j;
            tmp[q * 8 + j] = f2b(w[((size_t)(kc * 256 + cin)) * 256 + n]);
        }
#pragma unroll
    for (int i = 0; i < 4; ++i)
        *reinterpret_cast<uint4*>(o + i * 8) = *reinterpret_cast<const uint4*>(tmp + i * 8);
}

// ---------------------------------------------------------------------------
// Fused Conv1d(k=3,pad=1) + ReLU + LayerNorm (+ linear->exp head on SECOND)
// bf16 MFMA GEMM: M-tile=32 rows, N=256 (full width), K=768.
// A staged in LDS fragment-major, duplicated per tap (conflict-free b128).
// B streamed from fragment-major wQ (coalesced 1KB bursts, L2-resident),
// register double-buffered across K-steps (r2-proven pattern).
// Epilogue: round-2-verbatim (per-column LN + explicit head).
// ---------------------------------------------------------------------------
template <bool SECOND>
__global__ __launch_bounds__(256) void conv_mfma_kernel(
    const void* __restrict__ in_,              // conv1: float*, conv2: bf16(ushort)*
    const unsigned short* __restrict__ wQ,     // fragment-major weights
    const float* __restrict__ cbias,           // [256]
    const float* __restrict__ g,               // [256]
    const float* __restrict__ be,              // [256]
    const float* __restrict__ lin_w,           // [256] (SECOND)
    const float* __restrict__ lin_b,           // [1]   (SECOND)
    unsigned short* __restrict__ out_h,        // bf16 [B,L,256] (first layer)
    float* __restrict__ out_dur)               // [B,L] (SECOND)
{
    __shared__ union {
        unsigned short Af[48 * 64 * 8];        // 48 KB fragment-major A
        float outs[MT * OS];                   // 32.9 KB output tile
    } sm;
    __shared__ float red[4][MT][2];
    __shared__ float fin[MT][2];

    const int tid  = threadIdx.x;
    const int b    = blockIdx.x / (LL / MT);
    const int l0   = (blockIdx.x % (LL / MT)) * MT;
    const int wave = tid >> 6, lane = tid & 63;
    const int quad = lane >> 4, l16 = lane & 15;

    // ---- hoist epilogue constants (overlap scalar-load latency w/ K-loop) ----
    const int col = tid;
    const float biasv = cbias[col];
    const float gv  = g[col];
    const float bv  = be[col];
    const float lwv = SECOND ? lin_w[col] : 0.f;
    const float lbv = SECOND ? lin_b[0] : 0.f;

    // ---- stage A fragment-major (combo = (kc*8+c8)*2 + mt, 48 combos) ----
    for (int i = 0; i < 12; ++i) {
        const int combo = i * 4 + wave;
        const int mt = combo & 1;
        const int sc = combo >> 1;             // kc*8 + c8
        const int kc = sc >> 3, c8 = sc & 7;
        const int l  = l0 + mt * 16 + l16 + kc - 1;
        const int ch = c8 * 32 + quad * 8;
        bf16x8 val;
#pragma unroll
        for (int j = 0; j < 8; ++j) val[j] = 0;
        if (l >= 0 && l < LL) {
            if (!SECOND) {
                const float* p = (const float*)in_ + ((size_t)b * LL + l) * DD + ch;
                const float4 v0 = *reinterpret_cast<const float4*>(p);
                const float4 v1 = *reinterpret_cast<const float4*>(p + 4);
                val[0] = (short)f2b(v0.x); val[1] = (short)f2b(v0.y);
                val[2] = (short)f2b(v0.z); val[3] = (short)f2b(v0.w);
                val[4] = (short)f2b(v1.x); val[5] = (short)f2b(v1.y);
                val[6] = (short)f2b(v1.z); val[7] = (short)f2b(v1.w);
            } else {
                val = *reinterpret_cast<const bf16x8*>(
                    (const unsigned short*)in_ + ((size_t)b * LL + l) * DD + ch);
            }
        }
        *reinterpret_cast<bf16x8*>(&sm.Af[(combo * 64 + lane) * 8]) = val;
    }
    __syncthreads();

    // ---- K loop: 24 steps of 32, register double-buffered (r2 pattern) ----
    const unsigned short* aptr = &sm.Af[lane * 8];            // + s*1024 + mt*512
    const unsigned short* bptr = wQ + wave * 2048 + (l16 * 4 + quad) * 8;  // + s*8192 + nt*512

    f32x4 acc[2][4] = {};
    bf16x8 a_c[2], b_c[4];
#pragma unroll
    for (int mt = 0; mt < 2; ++mt)
        a_c[mt] = *reinterpret_cast<const bf16x8*>(aptr + mt * 512);
#pragma unroll
    for (int nt = 0; nt < 4; ++nt)
        b_c[nt] = *reinterpret_cast<const bf16x8*>(bptr + nt * 512);

    for (int s = 0; s < 24; ++s) {
        bf16x8 a_n[2], b_n[4];
        if (s < 23) {
#pragma unroll
            for (int mt = 0; mt < 2; ++mt)
                a_n[mt] = *reinterpret_cast<const bf16x8*>(aptr + (s + 1) * 1024 + mt * 512);
#pragma unroll
            for (int nt = 0; nt < 4; ++nt)
                b_n[nt] = *reinterpret_cast<const bf16x8*>(bptr + (size_t)(s + 1) * 8192 + nt * 512);
        }
#pragma unroll
        for (int mt = 0; mt < 2; ++mt)
#pragma unroll
            for (int nt = 0; nt < 4; ++nt)
                acc[mt][nt] = __builtin_amdgcn_mfma_f32_16x16x32_bf16(
                    a_c[mt], b_c[nt], acc[mt][nt], 0, 0, 0);
        if (s < 23) {
#pragma unroll
            for (int mt = 0; mt < 2; ++mt) a_c[mt] = a_n[mt];
#pragma unroll
            for (int nt = 0; nt < 4; ++nt) b_c[nt] = b_n[nt];
        }
    }
    __syncthreads();   // A-tile dead; reuse LDS for output tile

    // ---- scatter raw accumulators to LDS (C/D: col=lane&15, row=quad*4+reg) ----
#pragma unroll
    for (int mt = 0; mt < 2; ++mt)
#pragma unroll
        for (int nt = 0; nt < 4; ++nt)
#pragma unroll
            for (int r = 0; r < 4; ++r)
                sm.outs[(mt * 16 + quad * 4 + r) * OS + wave * 64 + nt * 16 + l16] =
                    acc[mt][nt][r];
    __syncthreads();

    // ---- round-2-verbatim epilogue: per-column bias/ReLU + LN + head ----
    float vv[MT];
#pragma unroll
    for (int r = 0; r < MT; ++r)
        vv[r] = fmaxf(sm.outs[r * OS + col] + biasv, 0.f);

#pragma unroll
    for (int r = 0; r < MT; ++r) {
        float v = vv[r];
        float sum = v, sq = v * v;
        for (int off = 32; off > 0; off >>= 1) {
            sum += __shfl_down(sum, off, 64);
            sq  += __shfl_down(sq,  off, 64);
        }
        if (lane == 0) { red[wave][r][0] = sum; red[wave][r][1] = sq; }
    }
    __syncthreads();
    if (tid < MT) {
        const float sum = red[0][tid][0] + red[1][tid][0] + red[2][tid][0] + red[3][tid][0];
        const float sq  = red[0][tid][1] + red[1][tid][1] + red[2][tid][1] + red[3][tid][1];
        const float mu  = sum / FF;
        const float var = sq / FF - mu * mu;
        fin[tid][0] = mu;
        fin[tid][1] = rsqrtf(var + 1e-5f);
    }
    __syncthreads();

#pragma unroll
    for (int r = 0; r < MT; ++r) {
        const float v = (vv[r] - fin[r][0]) * fin[r][1] * gv + bv;
        if (!SECOND) {
            out_h[((size_t)b * LL + l0 + r) * FF + col] = f2b(v);
        } else {
            float p = v * lwv;
            for (int off = 32; off > 0; off >>= 1) p += __shfl_down(p, off, 64);
            if (lane == 0) red[wave][r][0] = p;
        }
    }
    if (SECOND) {
        __syncthreads();
        if (tid < MT) {
            const float dp = red[0][tid][0] + red[1][tid][0] + red[2][tid][0]
                           + red[3][tid][0] + lbv;
            out_dur[(size_t)b * LL + l0 + tid] = expf(dp);
        }
    }
}

// ---------------------------------------------------------------------------
// dpo + cumsum + scatter idx map.  One block per batch row.
// ---------------------------------------------------------------------------
__global__ __launch_bounds__(256) void scan_kernel(
    const int* __restrict__ target,    // [B, L]
    float* __restrict__ out_dpo,       // [B, L] (stored as float)
    int* __restrict__ idx_map)         // [B, T]
{
    __shared__ int tsum[256];
    const int b = blockIdx.x, tid = threadIdx.x;

    const int l = 3 * tid;
    const int v0 = target[b * LL + l];
    const int v1 = target[b * LL + l + 1];
    const int v2 = target[b * LL + l + 2];
    out_dpo[b * LL + l]     = (float)v0;
    out_dpo[b * LL + l + 1] = (float)v1;
    out_dpo[b * LL + l + 2] = (float)v2;

    const int s0 = v0, s1 = v0 + v1, s2 = v0 + v1 + v2;
    tsum[tid] = s2;
    __syncthreads();
    for (int off = 1; off < 256; off <<= 1) {
        int x = (tid >= off) ? tsum[tid - off] : 0;
        __syncthreads();
        tsum[tid] += x;
        __syncthreads();
    }
    const int excl = tsum[tid] - s2;

    for (int t = tid; t < TT; t += 256) idx_map[b * TT + t] = -1;
    __syncthreads();

    const int c0 = excl + s0, c1 = excl + s1, c2 = excl + s2;
    for (int t = excl; t < c0 && t < TT; ++t) idx_map[b * TT + t] = l;
    for (int t = c0;   t < c1 && t < TT; ++t) idx_map[b * TT + t] = l + 1;
    for (int t = c1;   t < c2 && t < TT; ++t) idx_map[b * TT + t] = l + 2;
}

// ---------------------------------------------------------------------------
// Gather: out[b,t,:] = x[b, idx_map[b][t], :]  (zeros when masked)
// ---------------------------------------------------------------------------
__global__ __launch_bounds__(256) void gather_kernel(
    const float* __restrict__ x,       // [B, L, 256]
    const int* __restrict__ idx_map,   // [B, T]
    float* __restrict__ out)           // [B, T, 256]
{
    const int wv = threadIdx.x >> 6, lane = threadIdx.x & 63;
    const int row = blockIdx.x * 4 + wv;          // row in [0, B*T)
    const int b = row / TT, t = row - b * TT;
    const int idx = idx_map[b * TT + t];
    float4 val = make_float4(0.f, 0.f, 0.f, 0.f);
    if (idx >= 0)
        val = reinterpret_cast<const float4*>(x)[(size_t)(b * LL + idx) * (DD / 4) + lane];
    reinterpret_cast<float4*>(out)[(size_t)row * (DD / 4) + lane] = val;
}

// ---------------------------------------------------------------------------
extern "C" void kernel_launch(void* const* d_in, const int* in_sizes, int n_in,
                              void* d_out, int out_size, void* d_ws, size_t ws_size,
                              hipStream_t stream)
{
    const float* x      = (const float*)d_in[0];
    const int*   target = (const int*)  d_in[1];
    const float* c1w = (const float*)d_in[3];
    const float* c1b = (const float*)d_in[4];
    const float* g1  = (const float*)d_in[5];
    const float* b1  = (const float*)d_in[6];
    const float* c2w = (const float*)d_in[7];
    const float* c2b = (const float*)d_in[8];
    const float* g2  = (const float*)d_in[9];
    const float* b2  = (const float*)d_in[10];
    const float* lw  = (const float*)d_in[11];
    const float* lb  = (const float*)d_in[12];

    float* out0    = (float*)d_out;                       // [B, T, 256]
    float* out_dpo = out0 + (size_t)BB * TT * DD;         // [B, L]
    float* out_dur = out_dpo + (size_t)BB * LL;           // [B, L]

    // workspace layout
    char* ws = (char*)d_ws;
    unsigned short* wQ1 = (unsigned short*)ws;                 ws += (size_t)24 * 8192 * 2;
    unsigned short* wQ2 = (unsigned short*)ws;                 ws += (size_t)24 * 8192 * 2;
    unsigned short* h1b = (unsigned short*)ws;                 ws += (size_t)BB * LL * FF * 2;
    int* idx_map        = (int*)ws;

    prep_w_kernel<<<48, 256, 0, stream>>>(c1w, c2w, wQ1, wQ2);

    const int conv_grid = BB * (LL / MT);   // 768
    conv_mfma_kernel<false><<<conv_grid, 256, 0, stream>>>(
        x, wQ1, c1b, g1, b1, nullptr, nullptr, h1b, nullptr);
    conv_mfma_kernel<true><<<conv_grid, 256, 0, stream>>>(
        h1b, wQ2, c2b, g2, b2, lw, lb, nullptr, out_dur);

    scan_kernel<<<BB, 256, 0, stream>>>(target, out_dpo, idx_map);
    gather_kernel<<<BB * TT / 4, 256, 0, stream>>>(x, idx_map, out0);
}

// Round 7
// 209.004 us; speedup vs baseline: 1.1258x; 1.1258x over previous
//
#include <hip/hip_runtime.h>
#include <hip/hip_bf16.h>
#include <math.h>

// Problem constants (fixed by the reference)
#define BB 32
#define LL 768
#define DD 256
#define FF 256
#define TT 3072
#define MT 32              // dp output rows per block
#define PAD 264            // LDS row stride (bf16 elems)
#define A1R 50             // staged x rows: covers conv1 A-reads for 3 m-tiles

typedef __attribute__((ext_vector_type(8))) short bf16x8;
typedef __attribute__((ext_vector_type(4))) float f32x4;

__device__ inline unsigned short f2b(float f) {
    union { float f; unsigned u; } v; v.f = f;
    unsigned r = (v.u + 0x7FFF + ((v.u >> 16) & 1)) >> 16;  // RNE
    return (unsigned short)r;
}

// ---------------------------------------------------------------------------
// Weight prep into FRAGMENT-MAJOR layout (unchanged, r5-verified):
//   wQ[s*8192 + n*32 + q*8 + j] = bf16(w[kc][c8*32+q*8+j][n]),  s = kc*8+c8
// ---------------------------------------------------------------------------
__global__ __launch_bounds__(256) void prep_w_kernel(
    const float* __restrict__ w1, const float* __restrict__ w2,
    unsigned short* __restrict__ wQ1, unsigned short* __restrict__ wQ2)
{
    const int layer = blockIdx.x / 24;
    const int s  = blockIdx.x % 24;
    const int kc = s >> 3, c8 = s & 7;
    const float* __restrict__ w = layer ? w2 : w1;
    unsigned short* __restrict__ o = (layer ? wQ2 : wQ1) + s * 8192 + threadIdx.x * 32;
    const int n = threadIdx.x;

    alignas(16) unsigned short tmp[32];
#pragma unroll
    for (int q = 0; q < 4; ++q)
#pragma unroll
        for (int j = 0; j < 8; ++j) {
            const int cin = c8 * 32 + q * 8 + j;
            tmp[q * 8 + j] = f2b(w[((size_t)(kc * 256 + cin)) * 256 + n]);
        }
#pragma unroll
    for (int i = 0; i < 4; ++i)
        *reinterpret_cast<uint4*>(o + i * 8) = *reinterpret_cast<const uint4*>(tmp + i * 8);
}

// ---------------------------------------------------------------------------
// FUSED DurationPredictor: conv1+ReLU+LN1 (48 rows, LDS-local) ->
// conv2+ReLU+LN2+linear+exp (32 rows) in ONE kernel.  No h1 global traffic.
// LN stats via register-direct quad-group shfl_xor reductions on the MFMA
// C/D fragment layout (col=lane&15, row=quad*4+reg).  Head uses the direct
// reference formula (no fused algebra).
// ---------------------------------------------------------------------------
__global__ __launch_bounds__(256) void fused_dp_kernel(
    const float* __restrict__ x,               // [B, L, 256] fp32
    const unsigned short* __restrict__ wQ1,    // fragment-major conv1 weights
    const unsigned short* __restrict__ wQ2,    // fragment-major conv2 weights
    const float* __restrict__ c1b, const float* __restrict__ g1, const float* __restrict__ b1,
    const float* __restrict__ c2b, const float* __restrict__ g2, const float* __restrict__ b2,
    const float* __restrict__ lw,  const float* __restrict__ lb,
    float* __restrict__ out_dur)               // [B, L]
{
    __shared__ union {
        unsigned short A1[A1R * PAD];          // 26.4 KB staged x rows (bf16)
        unsigned short h2[34 * PAD];           // 17.9 KB LN'd conv1 rows (bf16)
    } sm;
    __shared__ float red[4][3][4][4][2];       // [wave][mt][quad][r][{s1,s2}]
    __shared__ float redp[4][2][4][4];         // [wave][mt2][quad][r] head partials
    __shared__ float fin[48][2];               // per-row (mu, rstd)

    const int tid  = threadIdx.x;
    const int b    = blockIdx.x / (LL / MT);
    const int l0   = (blockIdx.x % (LL / MT)) * MT;
    const int wave = tid >> 6, lane = tid & 63;
    const int quad = lane >> 4, l16 = lane & 15;

    // ---- hoist per-lane column constants (latency overlaps staging) ----
    int   cols[4];
    float c1bv[4], g1v[4], b1v[4], c2bv[4], g2v[4], b2v[4], lwv[4];
#pragma unroll
    for (int nt = 0; nt < 4; ++nt) {
        const int c = wave * 64 + nt * 16 + l16;
        cols[nt] = c;
        c1bv[nt] = c1b[c]; g1v[nt] = g1[c]; b1v[nt] = b1[c];
        c2bv[nt] = c2b[c]; g2v[nt] = g2[c]; b2v[nt] = b2[c];
        lwv[nt]  = lw[c];
    }
    const float lbv = lb[0];

    // ---- stage x rows l0-2 .. l0+47 (A1R=50) as bf16, zero-pad OOR ----
    {
        const int ch = (tid & 31) * 8;       // 8-channel group
        const int rr = tid >> 5;             // 0..7
        for (int p = 0; p < 7; ++p) {
            const int ar = p * 8 + rr;
            if (ar >= A1R) break;
            const int l = l0 - 2 + ar;
            bf16x8 val;
#pragma unroll
            for (int j = 0; j < 8; ++j) val[j] = 0;
            if (l >= 0 && l < LL) {
                const float* pp = x + ((size_t)b * LL + l) * DD + ch;
                const float4 v0 = *reinterpret_cast<const float4*>(pp);
                const float4 v1 = *reinterpret_cast<const float4*>(pp + 4);
                val[0] = (short)f2b(v0.x); val[1] = (short)f2b(v0.y);
                val[2] = (short)f2b(v0.z); val[3] = (short)f2b(v0.w);
                val[4] = (short)f2b(v1.x); val[5] = (short)f2b(v1.y);
                val[6] = (short)f2b(v1.z); val[7] = (short)f2b(v1.w);
            }
            *reinterpret_cast<bf16x8*>(&sm.A1[ar * PAD + ch]) = val;
        }
    }
    __syncthreads();

    // ---- conv1 K-loop: 3 m-tiles (h rows l0-1 .. l0+46), K=768 ----
    f32x4 acc1[3][4] = {};
    for (int s = 0; s < 24; ++s) {
        const int kc = s >> 3, c8 = s & 7;
        bf16x8 a[3], bf[4];
#pragma unroll
        for (int mt = 0; mt < 3; ++mt)
            a[mt] = *reinterpret_cast<const bf16x8*>(
                &sm.A1[(16 * mt + l16 + kc) * PAD + c8 * 32 + quad * 8]);
#pragma unroll
        for (int nt = 0; nt < 4; ++nt)
            bf[nt] = *reinterpret_cast<const bf16x8*>(
                wQ1 + (size_t)s * 8192 + cols[nt] * 32 + quad * 8);
#pragma unroll
        for (int mt = 0; mt < 3; ++mt)
#pragma unroll
            for (int nt = 0; nt < 4; ++nt)
                acc1[mt][nt] = __builtin_amdgcn_mfma_f32_16x16x32_bf16(
                    a[mt], bf[nt], acc1[mt][nt], 0, 0, 0);
    }
    __syncthreads();   // A1 dead

    // ---- LN1 stats: register-direct quad-group reduction ----
#pragma unroll
    for (int mt = 0; mt < 3; ++mt)
#pragma unroll
        for (int r = 0; r < 4; ++r) {
            float s1 = 0.f, s2 = 0.f;
#pragma unroll
            for (int nt = 0; nt < 4; ++nt) {
                const float v = fmaxf(acc1[mt][nt][r] + c1bv[nt], 0.f);
                s1 += v; s2 += v * v;
            }
            for (int m = 1; m < 16; m <<= 1) {
                s1 += __shfl_xor(s1, m, 64);
                s2 += __shfl_xor(s2, m, 64);
            }
            if (l16 == 0) { red[wave][mt][quad][r][0] = s1; red[wave][mt][quad][r][1] = s2; }
        }
    __syncthreads();
    if (tid < 48) {
        const int mt = tid >> 4, q = (tid >> 2) & 3, r = tid & 3;
        const float s1 = red[0][mt][q][r][0] + red[1][mt][q][r][0]
                       + red[2][mt][q][r][0] + red[3][mt][q][r][0];
        const float s2 = red[0][mt][q][r][1] + red[1][mt][q][r][1]
                       + red[2][mt][q][r][1] + red[3][mt][q][r][1];
        const float mu  = s1 * (1.f / 256.f);
        const float var = s2 * (1.f / 256.f) - mu * mu;
        fin[tid][0] = mu;
        fin[tid][1] = rsqrtf(var + 1e-5f);
    }
    __syncthreads();

    // ---- write h2 = LN1 rows (h rows l0-1..l0+32, zero outside sequence) ----
#pragma unroll
    for (int mt = 0; mt < 3; ++mt)
#pragma unroll
        for (int r = 0; r < 4; ++r) {
            const int rho = 16 * mt + quad * 4 + r;
            if (rho < 34) {
                const int gr = l0 - 1 + rho;          // global h row
                const float mu = fin[rho][0], rstd = fin[rho][1];
#pragma unroll
                for (int nt = 0; nt < 4; ++nt) {
                    unsigned short hv = 0;
                    if (gr >= 0 && gr < LL) {
                        const float v = fmaxf(acc1[mt][nt][r] + c1bv[nt], 0.f);
                        hv = f2b((v - mu) * rstd * g1v[nt] + b1v[nt]);
                    }
                    sm.h2[rho * PAD + cols[nt]] = hv;
                }
            }
        }
    __syncthreads();

    // ---- conv2 K-loop: 2 m-tiles (dp rows l0 .. l0+31), K=768 ----
    f32x4 acc2[2][4] = {};
    for (int s = 0; s < 24; ++s) {
        const int kc = s >> 3, c8 = s & 7;
        bf16x8 a[2], bf[4];
#pragma unroll
        for (int mt = 0; mt < 2; ++mt)
            a[mt] = *reinterpret_cast<const bf16x8*>(
                &sm.h2[(16 * mt + l16 + kc) * PAD + c8 * 32 + quad * 8]);
#pragma unroll
        for (int nt = 0; nt < 4; ++nt)
            bf[nt] = *reinterpret_cast<const bf16x8*>(
                wQ2 + (size_t)s * 8192 + cols[nt] * 32 + quad * 8);
#pragma unroll
        for (int mt = 0; mt < 2; ++mt)
#pragma unroll
            for (int nt = 0; nt < 4; ++nt)
                acc2[mt][nt] = __builtin_amdgcn_mfma_f32_16x16x32_bf16(
                    a[mt], bf[nt], acc2[mt][nt], 0, 0, 0);
    }

    // ---- LN2 stats ----
#pragma unroll
    for (int mt = 0; mt < 2; ++mt)
#pragma unroll
        for (int r = 0; r < 4; ++r) {
            float s1 = 0.f, s2 = 0.f;
#pragma unroll
            for (int nt = 0; nt < 4; ++nt) {
                const float v = fmaxf(acc2[mt][nt][r] + c2bv[nt], 0.f);
                s1 += v; s2 += v * v;
            }
            for (int m = 1; m < 16; m <<= 1) {
                s1 += __shfl_xor(s1, m, 64);
                s2 += __shfl_xor(s2, m, 64);
            }
            if (l16 == 0) { red[wave][mt][quad][r][0] = s1; red[wave][mt][quad][r][1] = s2; }
        }
    __syncthreads();
    if (tid < 32) {
        const int mt = tid >> 4, q = (tid >> 2) & 3, r = tid & 3;
        const float s1 = red[0][mt][q][r][0] + red[1][mt][q][r][0]
                       + red[2][mt][q][r][0] + red[3][mt][q][r][0];
        const float s2 = red[0][mt][q][r][1] + red[1][mt][q][r][1]
                       + red[2][mt][q][r][1] + red[3][mt][q][r][1];
        const float mu  = s1 * (1.f / 256.f);
        const float var = s2 * (1.f / 256.f) - mu * mu;
        fin[tid][0] = mu;
        fin[tid][1] = rsqrtf(var + 1e-5f);
    }
    __syncthreads();

    // ---- head: dp = sum_col LN2(v)*lw  (direct reference formula) ----
#pragma unroll
    for (int mt = 0; mt < 2; ++mt)
#pragma unroll
        for (int r = 0; r < 4; ++r) {
            const int rho = 16 * mt + quad * 4 + r;
            const float mu = fin[rho][0], rstd = fin[rho][1];
            float p = 0.f;
#pragma unroll
            for (int nt = 0; nt < 4; ++nt) {
                const float v = fmaxf(acc2[mt][nt][r] + c2bv[nt], 0.f);
                p += ((v - mu) * rstd * g2v[nt] + b2v[nt]) * lwv[nt];
            }
            for (int m = 1; m < 16; m <<= 1) p += __shfl_xor(p, m, 64);
            if (l16 == 0) redp[wave][mt][quad][r] = p;
        }
    __syncthreads();
    if (tid < 32) {
        const int mt = tid >> 4, q = (tid >> 2) & 3, r = tid & 3;
        const float dp = redp[0][mt][q][r] + redp[1][mt][q][r]
                       + redp[2][mt][q][r] + redp[3][mt][q][r] + lbv;
        out_dur[(size_t)b * LL + l0 + tid] = expf(dp);
    }
}

// ---------------------------------------------------------------------------
// dpo + cumsum + scatter idx map.  One block per batch row.
// ---------------------------------------------------------------------------
__global__ __launch_bounds__(256) void scan_kernel(
    const int* __restrict__ target,    // [B, L]
    float* __restrict__ out_dpo,       // [B, L] (stored as float)
    int* __restrict__ idx_map)         // [B, T]
{
    __shared__ int tsum[256];
    const int b = blockIdx.x, tid = threadIdx.x;

    const int l = 3 * tid;
    const int v0 = target[b * LL + l];
    const int v1 = target[b * LL + l + 1];
    const int v2 = target[b * LL + l + 2];
    out_dpo[b * LL + l]     = (float)v0;
    out_dpo[b * LL + l + 1] = (float)v1;
    out_dpo[b * LL + l + 2] = (float)v2;

    const int s0 = v0, s1 = v0 + v1, s2 = v0 + v1 + v2;
    tsum[tid] = s2;
    __syncthreads();
    for (int off = 1; off < 256; off <<= 1) {
        int xq = (tid >= off) ? tsum[tid - off] : 0;
        __syncthreads();
        tsum[tid] += xq;
        __syncthreads();
    }
    const int excl = tsum[tid] - s2;

    for (int t = tid; t < TT; t += 256) idx_map[b * TT + t] = -1;
    __syncthreads();

    const int c0 = excl + s0, c1 = excl + s1, c2 = excl + s2;
    for (int t = excl; t < c0 && t < TT; ++t) idx_map[b * TT + t] = l;
    for (int t = c0;   t < c1 && t < TT; ++t) idx_map[b * TT + t] = l + 1;
    for (int t = c1;   t < c2 && t < TT; ++t) idx_map[b * TT + t] = l + 2;
}

// ---------------------------------------------------------------------------
// Gather: out[b,t,:] = x[b, idx_map[b][t], :]  (zeros when masked)
// ---------------------------------------------------------------------------
__global__ __launch_bounds__(256) void gather_kernel(
    const float* __restrict__ x,       // [B, L, 256]
    const int* __restrict__ idx_map,   // [B, T]
    float* __restrict__ out)           // [B, T, 256]
{
    const int wv = threadIdx.x >> 6, lane = threadIdx.x & 63;
    const int row = blockIdx.x * 4 + wv;          // row in [0, B*T)
    const int b = row / TT, t = row - b * TT;
    const int idx = idx_map[b * TT + t];
    float4 val = make_float4(0.f, 0.f, 0.f, 0.f);
    if (idx >= 0)
        val = reinterpret_cast<const float4*>(x)[(size_t)(b * LL + idx) * (DD / 4) + lane];
    reinterpret_cast<float4*>(out)[(size_t)row * (DD / 4) + lane] = val;
}

// ---------------------------------------------------------------------------
extern "C" void kernel_launch(void* const* d_in, const int* in_sizes, int n_in,
                              void* d_out, int out_size, void* d_ws, size_t ws_size,
                              hipStream_t stream)
{
    const float* x      = (const float*)d_in[0];
    const int*   target = (const int*)  d_in[1];
    const float* c1w = (const float*)d_in[3];
    const float* c1b = (const float*)d_in[4];
    const float* g1  = (const float*)d_in[5];
    const float* b1  = (const float*)d_in[6];
    const float* c2w = (const float*)d_in[7];
    const float* c2b = (const float*)d_in[8];
    const float* g2  = (const float*)d_in[9];
    const float* b2  = (const float*)d_in[10];
    const float* lw  = (const float*)d_in[11];
    const float* lb  = (const float*)d_in[12];

    float* out0    = (float*)d_out;                       // [B, T, 256]
    float* out_dpo = out0 + (size_t)BB * TT * DD;         // [B, L]
    float* out_dur = out_dpo + (size_t)BB * LL;           // [B, L]

    // workspace layout
    char* ws = (char*)d_ws;
    unsigned short* wQ1 = (unsigned short*)ws;                 ws += (size_t)24 * 8192 * 2;
    unsigned short* wQ2 = (unsigned short*)ws;                 ws += (size_t)24 * 8192 * 2;
    int* idx_map        = (int*)ws;

    prep_w_kernel<<<48, 256, 0, stream>>>(c1w, c2w, wQ1, wQ2);

    fused_dp_kernel<<<BB * (LL / MT), 256, 0, stream>>>(
        x, wQ1, wQ2, c1b, g1, b1, c2b, g2, b2, lw, lb, out_dur);

    scan_kernel<<<BB, 256, 0, stream>>>(target, out_dpo, idx_map);
    gather_kernel<<<BB * TT / 4, 256, 0, stream>>>(x, idx_map, out0);
}

// Round 8
// 202.407 us; speedup vs baseline: 1.1625x; 1.0326x over previous
//
#include <hip/hip_runtime.h>
#include <hip/hip_bf16.h>
#include <math.h>

// Problem constants (fixed by the reference)
#define BB 32
#define LL 768
#define DD 256
#define FF 256
#define TT 3072
#define MT 48              // dp output rows per block -> grid 512 = 2 blocks/CU
#define PAD 262            // LDS row stride (bf16): dword stride 131 == 3 (mod 32)
                           // -> K-loop b128 start banks spread over all 32 (max 3-way)
#define A1R 66             // A1 rows (memory-safe read range 0..65; rows >=52 zeroed)

typedef __attribute__((ext_vector_type(8))) short bf16x8;
typedef __attribute__((ext_vector_type(4))) float f32x4;

__device__ inline unsigned short f2b(float f) {
    union { float f; unsigned u; } v; v.f = f;
    unsigned r = (v.u + 0x7FFF + ((v.u >> 16) & 1)) >> 16;  // RNE
    return (unsigned short)r;
}

// ---------------------------------------------------------------------------
// Weight prep into FRAGMENT-MAJOR layout (r5-verified):
//   wQ[s*8192 + n*32 + q*8 + j] = bf16(w[kc][c8*32+q*8+j][n]),  s = kc*8+c8
// ---------------------------------------------------------------------------
__global__ __launch_bounds__(256) void prep_w_kernel(
    const float* __restrict__ w1, const float* __restrict__ w2,
    unsigned short* __restrict__ wQ1, unsigned short* __restrict__ wQ2)
{
    const int layer = blockIdx.x / 24;
    const int s  = blockIdx.x % 24;
    const int kc = s >> 3, c8 = s & 7;
    const float* __restrict__ w = layer ? w2 : w1;
    unsigned short* __restrict__ o = (layer ? wQ2 : wQ1) + s * 8192 + threadIdx.x * 32;
    const int n = threadIdx.x;

    alignas(16) unsigned short tmp[32];
#pragma unroll
    for (int q = 0; q < 4; ++q)
#pragma unroll
        for (int j = 0; j < 8; ++j) {
            const int cin = c8 * 32 + q * 8 + j;
            tmp[q * 8 + j] = f2b(w[((size_t)(kc * 256 + cin)) * 256 + n]);
        }
#pragma unroll
    for (int i = 0; i < 4; ++i)
        *reinterpret_cast<uint4*>(o + i * 8) = *reinterpret_cast<const uint4*>(tmp + i * 8);
}

// ---------------------------------------------------------------------------
// FUSED DurationPredictor (r7 structure, MT=48, PAD=262):
// conv1+ReLU+LN1 (50 live rows, LDS-local) -> conv2+ReLU+LN2+linear+exp (48).
// LN stats via register-direct quad-group shfl_xor on the C/D layout
// (col=lane&15, row=quad*4+reg).  Head uses the direct reference formula.
// ---------------------------------------------------------------------------
__global__ __launch_bounds__(256) void fused_dp_kernel(
    const float* __restrict__ x,               // [B, L, 256] fp32
    const unsigned short* __restrict__ wQ1,    // fragment-major conv1 weights
    const unsigned short* __restrict__ wQ2,    // fragment-major conv2 weights
    const float* __restrict__ c1b, const float* __restrict__ g1, const float* __restrict__ b1,
    const float* __restrict__ c2b, const float* __restrict__ g2, const float* __restrict__ b2,
    const float* __restrict__ lw,  const float* __restrict__ lb,
    float* __restrict__ out_dur)               // [B, L]
{
    __shared__ union {
        unsigned short A1[A1R * PAD];          // 34.6 KB staged x rows (bf16)
        unsigned short h2[50 * PAD];           // 26.2 KB LN'd conv1 rows (bf16)
    } sm;
    __shared__ float red[4][4][4][4][2];       // [wave][mt][quad][r][{s1,s2}]
    __shared__ float redp[4][3][4][4];         // [wave][mt2][quad][r] head partials
    __shared__ float fin[50][2];               // per-row (mu, rstd)

    const int tid  = threadIdx.x;
    const int b    = blockIdx.x / (LL / MT);
    const int l0   = (blockIdx.x % (LL / MT)) * MT;
    const int wave = tid >> 6, lane = tid & 63;
    const int quad = lane >> 4, l16 = lane & 15;

    // ---- hoist per-lane column constants ----
    int   cols[4];
    float c1bv[4], g1v[4], b1v[4], c2bv[4], g2v[4], b2v[4], lwv[4];
#pragma unroll
    for (int nt = 0; nt < 4; ++nt) {
        const int c = wave * 64 + nt * 16 + l16;
        cols[nt] = c;
        c1bv[nt] = c1b[c]; g1v[nt] = g1[c]; b1v[nt] = b1[c];
        c2bv[nt] = c2b[c]; g2v[nt] = g2[c]; b2v[nt] = b2[c];
        lwv[nt]  = lw[c];
    }
    const float lbv = lb[0];

    // ---- stage x rows l0-2 .. l0+49 (ar<52) as bf16; rows 52..65 zeroed ----
    {
        const int ch = (tid & 31) * 8;       // 16B chunk within row
        const int rr = tid >> 5;             // 0..7
        for (int p = 0; p < 9; ++p) {
            const int ar = p * 8 + rr;
            if (ar >= A1R) break;
            const int l = l0 - 2 + ar;
            bf16x8 val;
#pragma unroll
            for (int j = 0; j < 8; ++j) val[j] = 0;
            if (ar < 52 && l >= 0 && l < LL) {
                const float* pp = x + ((size_t)b * LL + l) * DD + ch;
                const float4 v0 = *reinterpret_cast<const float4*>(pp);
                const float4 v1 = *reinterpret_cast<const float4*>(pp + 4);
                val[0] = (short)f2b(v0.x); val[1] = (short)f2b(v0.y);
                val[2] = (short)f2b(v0.z); val[3] = (short)f2b(v0.w);
                val[4] = (short)f2b(v1.x); val[5] = (short)f2b(v1.y);
                val[6] = (short)f2b(v1.z); val[7] = (short)f2b(v1.w);
            }
            *reinterpret_cast<bf16x8*>(&sm.A1[ar * PAD + ch]) = val;
        }
    }
    __syncthreads();

    // ---- conv1 K-loop: 4 m-tiles (h rows rho=0..63; rho>=50 discarded) ----
    f32x4 acc1[4][4] = {};
    for (int s = 0; s < 24; ++s) {
        const int kc = s >> 3, c8 = s & 7;
        bf16x8 a[4], bf[4];
#pragma unroll
        for (int mt = 0; mt < 4; ++mt)
            a[mt] = *reinterpret_cast<const bf16x8*>(
                &sm.A1[(16 * mt + l16 + kc) * PAD + c8 * 32 + quad * 8]);
#pragma unroll
        for (int nt = 0; nt < 4; ++nt)
            bf[nt] = *reinterpret_cast<const bf16x8*>(
                wQ1 + (size_t)s * 8192 + cols[nt] * 32 + quad * 8);
#pragma unroll
        for (int mt = 0; mt < 4; ++mt)
#pragma unroll
            for (int nt = 0; nt < 4; ++nt)
                acc1[mt][nt] = __builtin_amdgcn_mfma_f32_16x16x32_bf16(
                    a[mt], bf[nt], acc1[mt][nt], 0, 0, 0);
    }
    __syncthreads();   // A1 dead

    // ---- LN1 stats: register-direct quad-group reduction ----
#pragma unroll
    for (int mt = 0; mt < 4; ++mt)
#pragma unroll
        for (int r = 0; r < 4; ++r) {
            float s1 = 0.f, s2 = 0.f;
#pragma unroll
            for (int nt = 0; nt < 4; ++nt) {
                const float v = fmaxf(acc1[mt][nt][r] + c1bv[nt], 0.f);
                s1 += v; s2 += v * v;
            }
            for (int m = 1; m < 16; m <<= 1) {
                s1 += __shfl_xor(s1, m, 64);
                s2 += __shfl_xor(s2, m, 64);
            }
            if (l16 == 0) { red[wave][mt][quad][r][0] = s1; red[wave][mt][quad][r][1] = s2; }
        }
    __syncthreads();
    if (tid < 50) {
        const int mt = tid >> 4, q = (tid >> 2) & 3, r = tid & 3;
        const float s1 = red[0][mt][q][r][0] + red[1][mt][q][r][0]
                       + red[2][mt][q][r][0] + red[3][mt][q][r][0];
        const float s2 = red[0][mt][q][r][1] + red[1][mt][q][r][1]
                       + red[2][mt][q][r][1] + red[3][mt][q][r][1];
        const float mu  = s1 * (1.f / 256.f);
        const float var = s2 * (1.f / 256.f) - mu * mu;
        fin[tid][0] = mu;
        fin[tid][1] = rsqrtf(var + 1e-5f);
    }
    __syncthreads();

    // ---- write h2 = LN1 rows (h rows l0-1..l0+48; zero outside sequence) ----
#pragma unroll
    for (int mt = 0; mt < 4; ++mt)
#pragma unroll
        for (int r = 0; r < 4; ++r) {
            const int rho = 16 * mt + quad * 4 + r;
            if (rho < 50) {
                const int gr = l0 - 1 + rho;          // global h row
                const float mu = fin[rho][0], rstd = fin[rho][1];
#pragma unroll
                for (int nt = 0; nt < 4; ++nt) {
                    unsigned short hv = 0;
                    if (gr >= 0 && gr < LL) {
                        const float v = fmaxf(acc1[mt][nt][r] + c1bv[nt], 0.f);
                        hv = f2b((v - mu) * rstd * g1v[nt] + b1v[nt]);
                    }
                    sm.h2[rho * PAD + cols[nt]] = hv;
                }
            }
        }
    __syncthreads();

    // ---- conv2 K-loop: 3 m-tiles (dp rows l0 .. l0+47) ----
    f32x4 acc2[3][4] = {};
    for (int s = 0; s < 24; ++s) {
        const int kc = s >> 3, c8 = s & 7;
        bf16x8 a[3], bf[4];
#pragma unroll
        for (int mt = 0; mt < 3; ++mt)
            a[mt] = *reinterpret_cast<const bf16x8*>(
                &sm.h2[(16 * mt + l16 + kc) * PAD + c8 * 32 + quad * 8]);
#pragma unroll
        for (int nt = 0; nt < 4; ++nt)
            bf[nt] = *reinterpret_cast<const bf16x8*>(
                wQ2 + (size_t)s * 8192 + cols[nt] * 32 + quad * 8);
#pragma unroll
        for (int mt = 0; mt < 3; ++mt)
#pragma unroll
            for (int nt = 0; nt < 4; ++nt)
                acc2[mt][nt] = __builtin_amdgcn_mfma_f32_16x16x32_bf16(
                    a[mt], bf[nt], acc2[mt][nt], 0, 0, 0);
    }

    // ---- LN2 stats ----
#pragma unroll
    for (int mt = 0; mt < 3; ++mt)
#pragma unroll
        for (int r = 0; r < 4; ++r) {
            float s1 = 0.f, s2 = 0.f;
#pragma unroll
            for (int nt = 0; nt < 4; ++nt) {
                const float v = fmaxf(acc2[mt][nt][r] + c2bv[nt], 0.f);
                s1 += v; s2 += v * v;
            }
            for (int m = 1; m < 16; m <<= 1) {
                s1 += __shfl_xor(s1, m, 64);
                s2 += __shfl_xor(s2, m, 64);
            }
            if (l16 == 0) { red[wave][mt][quad][r][0] = s1; red[wave][mt][quad][r][1] = s2; }
        }
    __syncthreads();
    if (tid < MT) {
        const int mt = tid >> 4, q = (tid >> 2) & 3, r = tid & 3;
        const float s1 = red[0][mt][q][r][0] + red[1][mt][q][r][0]
                       + red[2][mt][q][r][0] + red[3][mt][q][r][0];
        const float s2 = red[0][mt][q][r][1] + red[1][mt][q][r][1]
                       + red[2][mt][q][r][1] + red[3][mt][q][r][1];
        const float mu  = s1 * (1.f / 256.f);
        const float var = s2 * (1.f / 256.f) - mu * mu;
        fin[tid][0] = mu;
        fin[tid][1] = rsqrtf(var + 1e-5f);
    }
    __syncthreads();

    // ---- head: dp = sum_col LN2(v)*lw  (direct reference formula) ----
#pragma unroll
    for (int mt = 0; mt < 3; ++mt)
#pragma unroll
        for (int r = 0; r < 4; ++r) {
            const int rho = 16 * mt + quad * 4 + r;
            const float mu = fin[rho][0], rstd = fin[rho][1];
            float p = 0.f;
#pragma unroll
            for (int nt = 0; nt < 4; ++nt) {
                const float v = fmaxf(acc2[mt][nt][r] + c2bv[nt], 0.f);
                p += ((v - mu) * rstd * g2v[nt] + b2v[nt]) * lwv[nt];
            }
            for (int m = 1; m < 16; m <<= 1) p += __shfl_xor(p, m, 64);
            if (l16 == 0) redp[wave][mt][quad][r] = p;
        }
    __syncthreads();
    if (tid < MT) {
        const int mt = tid >> 4, q = (tid >> 2) & 3, r = tid & 3;
        const float dp = redp[0][mt][q][r] + redp[1][mt][q][r]
                       + redp[2][mt][q][r] + redp[3][mt][q][r] + lbv;
        out_dur[(size_t)b * LL + l0 + tid] = expf(dp);
    }
}

// ---------------------------------------------------------------------------
// dpo + cumsum + scatter idx map.  One block per batch row.
// ---------------------------------------------------------------------------
__global__ __launch_bounds__(256) void scan_kernel(
    const int* __restrict__ target,    // [B, L]
    float* __restrict__ out_dpo,       // [B, L] (stored as float)
    int* __restrict__ idx_map)         // [B, T]
{
    __shared__ int tsum[256];
    const int b = blockIdx.x, tid = threadIdx.x;

    const int l = 3 * tid;
    const int v0 = target[b * LL + l];
    const int v1 = target[b * LL + l + 1];
    const int v2 = target[b * LL + l + 2];
    out_dpo[b * LL + l]     = (float)v0;
    out_dpo[b * LL + l + 1] = (float)v1;
    out_dpo[b * LL + l + 2] = (float)v2;

    const int s0 = v0, s1 = v0 + v1, s2 = v0 + v1 + v2;
    tsum[tid] = s2;
    __syncthreads();
    for (int off = 1; off < 256; off <<= 1) {
        int xq = (tid >= off) ? tsum[tid - off] : 0;
        __syncthreads();
        tsum[tid] += xq;
        __syncthreads();
    }
    const int excl = tsum[tid] - s2;

    for (int t = tid; t < TT; t += 256) idx_map[b * TT + t] = -1;
    __syncthreads();

    const int c0 = excl + s0, c1 = excl + s1, c2 = excl + s2;
    for (int t = excl; t < c0 && t < TT; ++t) idx_map[b * TT + t] = l;
    for (int t = c0;   t < c1 && t < TT; ++t) idx_map[b * TT + t] = l + 1;
    for (int t = c1;   t < c2 && t < TT; ++t) idx_map[b * TT + t] = l + 2;
}

// ---------------------------------------------------------------------------
// Gather: out[b,t,:] = x[b, idx_map[b][t], :]  (zeros when masked)
// ---------------------------------------------------------------------------
__global__ __launch_bounds__(256) void gather_kernel(
    const float* __restrict__ x,       // [B, L, 256]
    const int* __restrict__ idx_map,   // [B, T]
    float* __restrict__ out)           // [B, T, 256]
{
    const int wv = threadIdx.x >> 6, lane = threadIdx.x & 63;
    const int row = blockIdx.x * 4 + wv;          // row in [0, B*T)
    const int b = row / TT, t = row - b * TT;
    const int idx = idx_map[b * TT + t];
    float4 val = make_float4(0.f, 0.f, 0.f, 0.f);
    if (idx >= 0)
        val = reinterpret_cast<const float4*>(x)[(size_t)(b * LL + idx) * (DD / 4) + lane];
    reinterpret_cast<float4*>(out)[(size_t)row * (DD / 4) + lane] = val;
}

// ---------------------------------------------------------------------------
extern "C" void kernel_launch(void* const* d_in, const int* in_sizes, int n_in,
                              void* d_out, int out_size, void* d_ws, size_t ws_size,
                              hipStream_t stream)
{
    const float* x      = (const float*)d_in[0];
    const int*   target = (const int*)  d_in[1];
    const float* c1w = (const float*)d_in[3];
    const float* c1b = (const float*)d_in[4];
    const float* g1  = (const float*)d_in[5];
    const float* b1  = (const float*)d_in[6];
    const float* c2w = (const float*)d_in[7];
    const float* c2b = (const float*)d_in[8];
    const float* g2  = (const float*)d_in[9];
    const float* b2  = (const float*)d_in[10];
    const float* lw  = (const float*)d_in[11];
    const float* lb  = (const float*)d_in[12];

    float* out0    = (float*)d_out;                       // [B, T, 256]
    float* out_dpo = out0 + (size_t)BB * TT * DD;         // [B, L]
    float* out_dur = out_dpo + (size_t)BB * LL;           // [B, L]

    // workspace layout
    char* ws = (char*)d_ws;
    unsigned short* wQ1 = (unsigned short*)ws;                 ws += (size_t)24 * 8192 * 2;
    unsigned short* wQ2 = (unsigned short*)ws;                 ws += (size_t)24 * 8192 * 2;
    int* idx_map        = (int*)ws;

    prep_w_kernel<<<48, 256, 0, stream>>>(c1w, c2w, wQ1, wQ2);

    fused_dp_kernel<<<BB * (LL / MT), 256, 0, stream>>>(
        x, wQ1, wQ2, c1b, g1, b1, c2b, g2, b2, lw, lb, out_dur);

    scan_kernel<<<BB, 256, 0, stream>>>(target, out_dpo, idx_map);
    gather_kernel<<<BB * TT / 4, 256, 0, stream>>>(x, idx_map, out0);
}